// Round 2
// baseline (72.601 us; speedup 1.0000x reference)
//
#include <hip/hip_runtime.h>

// GaussianAnsatzNN: out[k,d] = N * sum_m theta[m] * exp(-0.5*||x_k - mu_m||^2) * (mu_{m,d} - x_{k,d})
// Means are a separable 20^3 grid -> Gaussian factorizes Ex_i*Ey_j*Ez_l; the
// m-sum becomes tensor contractions (262M FMA total instead of 131M exps).
//
// Single kernel, no atomics, no memset:
//   block = 256 threads = NCH(4) i-chunks x KB(64) k's (chunk is wave-uniform)
//   per thread: IC(5) i's, j-loop x 20, inner l-contraction of 20 via float4 LDS
//   broadcast reads; 4-chunk partials reduced in LDS; one coalesced store.

#define NG   20
#define MTOT 8000         // NG^3
#define KB   64           // k's per block
#define NCH  4            // i-chunks per block
#define IC   (NG / NCH)   // 5 i's per chunk
#define NT   (KB * NCH)   // 256 threads

__global__ __launch_bounds__(NT) void gauss_factored_kernel(
    const float* __restrict__ x, const float* __restrict__ means,
    const float* __restrict__ theta, float* __restrict__ out) {
  __shared__ float sth[MTOT];           // theta, 32 KB
  __shared__ float sg[3 * NG];          // per-axis grid values
  __shared__ float sred[NCH * KB * 3];  // partials, 3 KB

  const int tid = threadIdx.x;

  // Stage theta into LDS (float4; 8000/4 = 2000).
  {
    const float4* th4 = (const float4*)theta;
    float4* sth4 = (float4*)sth;
    for (int idx = tid; idx < MTOT / 4; idx += NT) sth4[idx] = th4[idx];
  }
  // Grid axis values: g_i = means[(i*400)*3+0], g_j = means[(j*20)*3+1], g_l = means[l*3+2]
  if (tid < 3 * NG) {
    int axis = tid / NG, p = tid % NG;
    int m = (axis == 0) ? p * 400 : (axis == 1) ? p * 20 : p;
    sg[tid] = means[m * 3 + axis];
  }
  __syncthreads();

  const int klocal = tid & (KB - 1);
  const int chunk = tid >> 6;  // wave-uniform (KB == wave size)
  const int k = blockIdx.x * KB + klocal;
  const float x0 = x[k * 3 + 0];
  const float x1 = x[k * 3 + 1];
  const float x2 = x[k * 3 + 2];

  // z-axis factors live in registers (40 VGPRs).
  float Ez[NG], Ezp[NG];
#pragma unroll
  for (int l = 0; l < NG; ++l) {
    float dz = x2 - sg[2 * NG + l];
    float e = __expf(-0.5f * dz * dz);
    Ez[l] = e;
    Ezp[l] = -dz * e;  // Ez_l * (g_l - x2)
  }

  const int i0 = chunk * IC;
  float ex[IC], exn[IC];
#pragma unroll
  for (int ii = 0; ii < IC; ++ii) {
    float dx = x0 - sg[i0 + ii];
    float e = __expf(-0.5f * dx * dx);
    ex[ii] = e;
    exn[ii] = -dx * e;  // Ex_i * (g_i - x0)
  }

  float b[IC], b1[IC], b2[IC];
#pragma unroll
  for (int ii = 0; ii < IC; ++ii) { b[ii] = 0.f; b1[ii] = 0.f; b2[ii] = 0.f; }

#pragma unroll 4
  for (int j = 0; j < NG; ++j) {
    const float dy = x1 - sg[NG + j];
    const float Ey = __expf(-0.5f * dy * dy);
    const float Eyp = -dy * Ey;  // Ey_j * (g_j - x1)
#pragma unroll
    for (int ii = 0; ii < IC; ++ii) {
      const float4* trow = (const float4*)&sth[(i0 + ii) * 400 + j * NG];  // wave-uniform -> broadcast
      float aZ0 = 0.f, aZ1 = 0.f, aZp0 = 0.f, aZp1 = 0.f;
#pragma unroll
      for (int l4 = 0; l4 < 5; ++l4) {
        const float4 t = trow[l4];
        aZ0  = fmaf(t.x, Ez [4 * l4 + 0], aZ0);
        aZp0 = fmaf(t.x, Ezp[4 * l4 + 0], aZp0);
        aZ1  = fmaf(t.y, Ez [4 * l4 + 1], aZ1);
        aZp1 = fmaf(t.y, Ezp[4 * l4 + 1], aZp1);
        aZ0  = fmaf(t.z, Ez [4 * l4 + 2], aZ0);
        aZp0 = fmaf(t.z, Ezp[4 * l4 + 2], aZp0);
        aZ1  = fmaf(t.w, Ez [4 * l4 + 3], aZ1);
        aZp1 = fmaf(t.w, Ezp[4 * l4 + 3], aZp1);
      }
      const float aZ = aZ0 + aZ1;
      const float aZp = aZp0 + aZp1;
      b[ii]  = fmaf(Ey,  aZ,  b[ii]);
      b1[ii] = fmaf(Eyp, aZ,  b1[ii]);
      b2[ii] = fmaf(Ey,  aZp, b2[ii]);
    }
  }

  float o0 = 0.f, o1 = 0.f, o2 = 0.f;
#pragma unroll
  for (int ii = 0; ii < IC; ++ii) {
    o0 = fmaf(exn[ii], b[ii], o0);
    o1 = fmaf(ex[ii], b1[ii], o1);
    o2 = fmaf(ex[ii], b2[ii], o2);
  }

  // Partials -> LDS (stride-3 across lanes: 2 lanes/bank, conflict-free).
  sred[chunk * (KB * 3) + klocal * 3 + 0] = o0;
  sred[chunk * (KB * 3) + klocal * 3 + 1] = o1;
  sred[chunk * (KB * 3) + klocal * 3 + 2] = o2;
  __syncthreads();

  // Reduce 4 chunks and store 192 consecutive floats per block.
  if (tid < KB * 3) {
    const float Nc = 0.06349363593424097f;  // (2*pi)^{-3/2}
    float s = sred[tid] + sred[KB * 3 + tid] + sred[2 * KB * 3 + tid] + sred[3 * KB * 3 + tid];
    out[blockIdx.x * (KB * 3) + tid] = s * Nc;
  }
}

extern "C" void kernel_launch(void* const* d_in, const int* in_sizes, int n_in,
                              void* d_out, int out_size, void* d_ws, size_t ws_size,
                              hipStream_t stream) {
  const float* x = (const float*)d_in[0];      // (K, 3)
  const float* means = (const float*)d_in[1];  // (8000, 3)
  const float* theta = (const float*)d_in[2];  // (8000,)
  float* out = (float*)d_out;                  // (K, 3)

  const int K = in_sizes[0] / 3;  // 16384

  gauss_factored_kernel<<<dim3(K / KB), NT, 0, stream>>>(x, means, theta, out);
}

// Round 3
// 70.616 us; speedup vs baseline: 1.0281x; 1.0281x over previous
//
#include <hip/hip_runtime.h>

// GaussianAnsatzNN: out[k,d] = N * sum_m theta[m] * exp(-0.5*||x_k - mu_m||^2) * (mu_{m,d} - x_{k,d})
// Separable 20^3 grid -> factorize into Ex_i*Ey_j*Ez_l tensor contractions.
//
// R3: LDS-pipe relief. Each thread handles KPT=2 k's so every wave-uniform
// broadcast ds_read_b128 of theta feeds 16 FMAs (was 8). Grid 128 kg x 5 cg,
// 4 waves/block = 4 i's (IC=1) -> 2560 waves (2.5/SIMD). Cross-block i-split
// accumulated via d_ws partials + tiny reduce kernel (no atomics, no memset).

#define NG    20
#define MTOT  8000          // NG^3
#define NT    256           // threads per block (4 waves)
#define KPT   2             // k's per thread
#define KPB   128           // k's per block = 64 * KPT
#define IPB   4             // i's per block (one per wave)
#define NCG   5             // i chunk-groups (blocks in y); NCG*IPB = NG

__global__ __launch_bounds__(NT) void gauss_main(
    const float* __restrict__ x, const float* __restrict__ means,
    const float* __restrict__ theta, float* __restrict__ ws, int K) {
  __shared__ float sth[MTOT];            // theta, 32 KB
  __shared__ float sg[3 * NG];           // per-axis grid values
  __shared__ float sred[IPB][KPB * 3];   // 6 KB partials

  const int tid = threadIdx.x;

  // Stage theta (float4; 2000 iters over 256 threads).
  {
    const float4* th4 = (const float4*)theta;
    float4* s4 = (float4*)sth;
    for (int idx = tid; idx < MTOT / 4; idx += NT) s4[idx] = th4[idx];
  }
  // Axis grid values: g_i = means[(i*400)*3+0], g_j = means[(j*20)*3+1], g_l = means[l*3+2]
  if (tid < 3 * NG) {
    int axis = tid / NG, p = tid % NG;
    int m = (axis == 0) ? p * 400 : (axis == 1) ? p * 20 : p;
    sg[tid] = means[m * 3 + axis];
  }
  __syncthreads();

  const int lane = tid & 63;
  const int wv = tid >> 6;                    // 0..3, wave-uniform
  const int i = blockIdx.y * IPB + wv;        // this wave's gaussian x-index
  const int k0 = blockIdx.x * KPB + lane;
  const int k1 = k0 + 64;

  const float x00 = x[k0 * 3 + 0], x01 = x[k0 * 3 + 1], x02 = x[k0 * 3 + 2];
  const float x10 = x[k1 * 3 + 0], x11 = x[k1 * 3 + 1], x12 = x[k1 * 3 + 2];

  // z-axis factors for both k's (80 VGPRs).
  float Ez0[NG], Ezp0[NG], Ez1[NG], Ezp1[NG];
#pragma unroll
  for (int l = 0; l < NG; ++l) {
    const float g = sg[2 * NG + l];
    const float dz0 = x02 - g;
    const float e0 = __expf(-0.5f * dz0 * dz0);
    Ez0[l] = e0; Ezp0[l] = -dz0 * e0;
    const float dz1 = x12 - g;
    const float e1 = __expf(-0.5f * dz1 * dz1);
    Ez1[l] = e1; Ezp1[l] = -dz1 * e1;
  }

  const float gi = sg[i];
  const float dx0 = x00 - gi, dx1 = x10 - gi;
  const float ex0 = __expf(-0.5f * dx0 * dx0), ex1 = __expf(-0.5f * dx1 * dx1);
  const float exn0 = -dx0 * ex0, exn1 = -dx1 * ex1;

  float A0 = 0.f, A1 = 0.f, A2 = 0.f;  // k0: (x', y', z') contractions
  float B0 = 0.f, B1 = 0.f, B2 = 0.f;  // k1
  const float4* trow = (const float4*)&sth[i * 400];  // wave-uniform -> LDS broadcast

#pragma unroll 2
  for (int j = 0; j < NG; ++j) {
    const float gj = sg[NG + j];
    const float dy0 = x01 - gj, dy1 = x11 - gj;
    const float Ey0 = __expf(-0.5f * dy0 * dy0);
    const float Ey1 = __expf(-0.5f * dy1 * dy1);
    const float Eyp0 = -dy0 * Ey0, Eyp1 = -dy1 * Ey1;

    // 8 independent accumulator chains for ILP.
    float z0 = 0.f, zp0 = 0.f, z1 = 0.f, zp1 = 0.f;
    float y0 = 0.f, yp0 = 0.f, y1 = 0.f, yp1 = 0.f;
#pragma unroll
    for (int l4 = 0; l4 < 5; ++l4) {
      const float4 t = trow[j * 5 + l4];
      z0  = fmaf(t.x, Ez0 [4 * l4 + 0], z0);
      zp0 = fmaf(t.x, Ezp0[4 * l4 + 0], zp0);
      z1  = fmaf(t.x, Ez1 [4 * l4 + 0], z1);
      zp1 = fmaf(t.x, Ezp1[4 * l4 + 0], zp1);
      y0  = fmaf(t.y, Ez0 [4 * l4 + 1], y0);
      yp0 = fmaf(t.y, Ezp0[4 * l4 + 1], yp0);
      y1  = fmaf(t.y, Ez1 [4 * l4 + 1], y1);
      yp1 = fmaf(t.y, Ezp1[4 * l4 + 1], yp1);
      z0  = fmaf(t.z, Ez0 [4 * l4 + 2], z0);
      zp0 = fmaf(t.z, Ezp0[4 * l4 + 2], zp0);
      z1  = fmaf(t.z, Ez1 [4 * l4 + 2], z1);
      zp1 = fmaf(t.z, Ezp1[4 * l4 + 2], zp1);
      y0  = fmaf(t.w, Ez0 [4 * l4 + 3], y0);
      yp0 = fmaf(t.w, Ezp0[4 * l4 + 3], yp0);
      y1  = fmaf(t.w, Ez1 [4 * l4 + 3], y1);
      yp1 = fmaf(t.w, Ezp1[4 * l4 + 3], yp1);
    }
    const float aZ0 = z0 + y0, aZp0 = zp0 + yp0;
    const float aZ1 = z1 + y1, aZp1 = zp1 + yp1;
    A0 = fmaf(Ey0,  aZ0,  A0);
    A1 = fmaf(Eyp0, aZ0,  A1);
    A2 = fmaf(Ey0,  aZp0, A2);
    B0 = fmaf(Ey1,  aZ1,  B0);
    B1 = fmaf(Eyp1, aZ1,  B1);
    B2 = fmaf(Ey1,  aZp1, B2);
  }

  // Per-wave partials -> LDS (stride-3: 2 lanes/bank, free).
  sred[wv][lane * 3 + 0] = exn0 * A0;
  sred[wv][lane * 3 + 1] = ex0 * A1;
  sred[wv][lane * 3 + 2] = ex0 * A2;
  sred[wv][192 + lane * 3 + 0] = exn1 * B0;
  sred[wv][192 + lane * 3 + 1] = ex1 * B1;
  sred[wv][192 + lane * 3 + 2] = ex1 * B2;
  __syncthreads();

  // Sum the block's 4 i's, write this chunk-group's partial (coalesced).
  float* wdst = ws + (size_t)blockIdx.y * (size_t)(K * 3) + (size_t)blockIdx.x * (KPB * 3);
  for (int idx = tid; idx < KPB * 3; idx += NT) {
    wdst[idx] = sred[0][idx] + sred[1][idx] + sred[2][idx] + sred[3][idx];
  }
}

__global__ __launch_bounds__(256) void gauss_reduce(
    const float* __restrict__ ws, float* __restrict__ out, int n4) {
  const int idx = blockIdx.x * 256 + threadIdx.x;
  if (idx >= n4) return;
  const float4* w4 = (const float4*)ws;
  const float4 a = w4[idx];
  const float4 b = w4[n4 + idx];
  const float4 c = w4[2 * n4 + idx];
  const float4 d = w4[3 * n4 + idx];
  const float4 e = w4[4 * n4 + idx];
  const float Nc = 0.06349363593424097f;  // (2*pi)^{-3/2}
  float4 r;
  r.x = (a.x + b.x + c.x + d.x + e.x) * Nc;
  r.y = (a.y + b.y + c.y + d.y + e.y) * Nc;
  r.z = (a.z + b.z + c.z + d.z + e.z) * Nc;
  r.w = (a.w + b.w + c.w + d.w + e.w) * Nc;
  ((float4*)out)[idx] = r;
}

extern "C" void kernel_launch(void* const* d_in, const int* in_sizes, int n_in,
                              void* d_out, int out_size, void* d_ws, size_t ws_size,
                              hipStream_t stream) {
  const float* x = (const float*)d_in[0];      // (K, 3)
  const float* means = (const float*)d_in[1];  // (8000, 3)
  const float* theta = (const float*)d_in[2];  // (8000,)
  float* out = (float*)d_out;                  // (K, 3)
  float* ws = (float*)d_ws;                    // NCG partial buffers of K*3 floats

  const int K = in_sizes[0] / 3;  // 16384

  gauss_main<<<dim3(K / KPB, NCG), NT, 0, stream>>>(x, means, theta, ws, K);

  const int n4 = (K * 3) / 4;  // 12288 float4's
  gauss_reduce<<<dim3((n4 + 255) / 256), 256, 0, stream>>>(ws, out, n4);
}